// Round 16
// baseline (159.903 us; speedup 1.0000x reference)
//
#include <hip/hip_runtime.h>
#include <stdint.h>

#define DIM 768
#define NHEAD 12
#define HD 64
#define B_ 8
#define SPEC 4
#define T_ 8
#define AP 196
#define VP 196
#define MQ (VP*T_)      // 1568
#define NKV (AP*SPEC)   // 784
#define NG2 50          // 16-col V groups per bh (49 used + 1 overread pad)
#define QSCALE 0.1803368801111618f   // 0.125 * log2(e): softmax done in exp2 domain

typedef short bf16x8 __attribute__((ext_vector_type(8)));
typedef short bf16x4 __attribute__((ext_vector_type(4)));
typedef float f32x4 __attribute__((ext_vector_type(4)));

__device__ __forceinline__ ushort f2bf(float f) {
    union { float f; unsigned u; } v; v.f = f;
    unsigned u = v.u;
    return (ushort)((u + 0x7fffu + ((u >> 16) & 1u)) >> 16);
}

__device__ __forceinline__ float fexp2(float x) {
    float r;
    asm("v_exp_f32 %0, %1" : "=v"(r) : "v"(x));
    return r;   // 2^x
}

// pack two f32 -> {lo = trunc-bf16(a), hi = trunc-bf16(b)} (proven bit-op path)
__device__ __forceinline__ unsigned pk2(float a, float b) {
    union { float f; unsigned u; } ua, ub; ua.f = a; ub.f = b;
    return (ub.u & 0xFFFF0000u) | (ua.u >> 16);
}

typedef const __attribute__((address_space(1))) void GV;
typedef __attribute__((address_space(3))) void LV;
__device__ __forceinline__ void gload16(const void* g, void* l) {
    __builtin_amdgcn_global_load_lds((GV*)g, (LV*)l, 16, 0, 0);
}

// ---------------- merged prep kernel (range-dispatched) ----------------

__global__ void prep_all_k(const float* __restrict__ t_x,
                           const float* __restrict__ vsp,
                           const float* __restrict__ vtp,
                           const float* __restrict__ s_x,
                           const float* __restrict__ csp,
                           const float* __restrict__ ctp,
                           const float* __restrict__ Wq,
                           const float* __restrict__ Wkv,
                           const float* __restrict__ Wpj,
                           ushort* __restrict__ qin,
                           ushort* __restrict__ sb,
                           ushort* __restrict__ wqb,
                           ushort* __restrict__ wkvb,
                           ushort* __restrict__ wpjb,
                           float* __restrict__ out) {
    int bid = blockIdx.x;
    if (bid < 9408) {
        int i = bid * 256 + threadIdx.x;
        int d4 = i % (DIM / 4);
        int rest = i / (DIM / 4);
        int m = rest % MQ;
        int b = rest / MQ;
        int vp = m >> 3, t = m & 7;
        const float4 a  = *(const float4*)(t_x + ((size_t)(1 + vp) * (B_ * T_) + b * T_ + t) * DIM + d4 * 4);
        const float4 p1 = *(const float4*)(vsp + (size_t)vp * DIM + d4 * 4);
        const float4 p2 = *(const float4*)(vtp + (size_t)t * DIM + d4 * 4);
        ushort4 r;
        r.x = f2bf(a.x + p1.x + p2.x);
        r.y = f2bf(a.y + p1.y + p2.y);
        r.z = f2bf(a.z + p1.z + p2.z);
        r.w = f2bf(a.w + p1.w + p2.w);
        *(ushort4*)(qin + ((size_t)(b * MQ + m)) * DIM + d4 * 4) = r;
    } else if (bid < 14112) {
        int i = (bid - 9408) * 256 + threadIdx.x;
        int d4 = i % (DIM / 4);
        int rest = i / (DIM / 4);
        int n = rest % NKV;
        int b = rest / NKV;
        int ap = n >> 2, spec = n & 3;
        const float4 a  = *(const float4*)(s_x + ((size_t)ap * (B_ * SPEC) + b * SPEC + spec) * DIM + d4 * 4);
        const float4 p1 = *(const float4*)(csp + (size_t)ap * DIM + d4 * 4);
        const float4 p2 = *(const float4*)(ctp + (size_t)spec * DIM + d4 * 4);
        ushort4 r;
        r.x = f2bf(a.x + p1.x + p2.x);
        r.y = f2bf(a.y + p1.y + p2.y);
        r.z = f2bf(a.z + p1.z + p2.z);
        r.w = f2bf(a.w + p1.w + p2.w);
        *(ushort4*)(sb + ((size_t)(b * NKV + n)) * DIM + d4 * 4) = r;
    } else if (bid < 16416) {
        const float* src; ushort* dst; int i;
        if (bid < 14688)      { src = Wq;  dst = wqb;  i = (bid - 14112) * 256 + threadIdx.x; }
        else if (bid < 15840) { src = Wkv; dst = wkvb; i = (bid - 14688) * 256 + threadIdx.x; }
        else                  { src = Wpj; dst = wpjb; i = (bid - 15840) * 256 + threadIdx.x; }
        float4 v = *(const float4*)(src + (size_t)i * 4);
        ushort4 r;
        r.x = f2bf(v.x); r.y = f2bf(v.y); r.z = f2bf(v.z); r.w = f2bf(v.w);
        *(ushort4*)(dst + (size_t)i * 4) = r;
    } else {
        int i = (bid - 16416) * 256 + threadIdx.x;
        *(float4*)(out + (size_t)i * 4) = *(const float4*)(t_x + (size_t)i * 4);
    }
}

// ---------------- GEMM core (128x128 tile, BK=32, 4 waves, bf16 MFMA) ----------------
// MODE 1 V half stores into the PACKED fragment layout:
// vpk[bh][g2][d][c], g2 = n/16, c = n%16  (each (mi,ni) tile = one 512B block)

template <int MODE>
__device__ __forceinline__ void gemm_body(ushort* As, ushort* Bs,
                                          const ushort* __restrict__ A,
                                          const ushort* __restrict__ Bw,
                                          const float* __restrict__ bias,
                                          ushort* __restrict__ out_a,
                                          ushort* __restrict__ out_b,
                                          float* __restrict__ out_f,
                                          int m0, int n0) {
    const int tid = threadIdx.x;
    const int lane = tid & 63, wid = tid >> 6;
    const int wm = wid >> 1, wn = wid & 1;
    const int lr = lane & 15, hi = lane >> 4;

    const int srow = wid * 32 + (lane >> 2);
    const int scolb = (lane & 3) * 16;
    const char* gA = (const char*)A + ((size_t)(m0 + srow) * DIM) * 2 + scolb;
    const char* gB = (const char*)Bw + ((size_t)(n0 + srow) * DIM) * 2 + scolb;
    const size_t radv = (size_t)16 * DIM * 2;
    char* lA = (char*)As + wid * 2048;
    char* lB = (char*)Bs + wid * 2048;

    f32x4 acc[4][4] = {};

    for (int k0 = 0; k0 < DIM; k0 += 32) {
        size_t ko = (size_t)k0 * 2;
        gload16(gA + ko,        lA);
        gload16(gA + ko + radv, lA + 1024);
        gload16(gB + ko,        lB);
        gload16(gB + ko + radv, lB + 1024);
        __syncthreads();
        bf16x8 af[4], bfr[4];
#pragma unroll
        for (int x = 0; x < 4; ++x) {
            af[x]  = *(const bf16x8*)&As[(wm * 64 + x * 16 + lr) * 32 + hi * 8];
            bfr[x] = *(const bf16x8*)&Bs[(wn * 64 + x * 16 + lr) * 32 + hi * 8];
        }
#pragma unroll
        for (int mi = 0; mi < 4; ++mi)
#pragma unroll
            for (int ni = 0; ni < 4; ++ni)
                acc[mi][ni] = __builtin_amdgcn_mfma_f32_16x16x32_bf16(af[mi], bfr[ni], acc[mi][ni], 0, 0, 0);
        __syncthreads();
    }

#pragma unroll
    for (int mi = 0; mi < 4; ++mi) {
#pragma unroll
        for (int ni = 0; ni < 4; ++ni) {
            int gn = n0 + wn * 64 + ni * 16 + lr;
            float bv = bias[gn];
            if (MODE == 1 && gn >= DIM) {
                int o2 = gn - DIM;
                int hh = o2 >> 6, d = o2 & 63;
                int gm0 = m0 + wm * 64 + mi * 16 + hi * 4;
                int b = gm0 / NKV, n = gm0 % NKV;
                int bh = b * NHEAD + hh;
                int g2 = n >> 4, c = n & 15;
                ushort4 pk;
                pk.x = f2bf(acc[mi][ni][0] + bv);
                pk.y = f2bf(acc[mi][ni][1] + bv);
                pk.z = f2bf(acc[mi][ni][2] + bv);
                pk.w = f2bf(acc[mi][ni][3] + bv);
                *(ushort4*)&out_b[(((size_t)(bh * NG2 + g2)) * 64 + d) * 16 + c] = pk;
                continue;
            }
#pragma unroll
            for (int r = 0; r < 4; ++r) {
                int gm = m0 + wm * 64 + mi * 16 + hi * 4 + r;
                float val = acc[mi][ni][r] + bv;
                if (MODE == 0) {
                    int b = gm / MQ, m = gm % MQ;
                    int hh = gn >> 6, d = gn & 63;
                    out_a[(((size_t)(b * NHEAD + hh)) * MQ + m) * HD + d] = f2bf(val * QSCALE);
                } else if (MODE == 1) {
                    int b = gm / NKV, n = gm % NKV;
                    int hh = gn >> 6, d = gn & 63;
                    out_a[(((size_t)(b * NHEAD + hh)) * NKV + n) * HD + d] = f2bf(val);
                } else {
                    int b = gm / MQ, m = gm % MQ;
                    int vp = m >> 3, tt = m & 7;
                    out_f[((size_t)(1 + vp) * (B_ * T_) + b * T_ + tt) * DIM + gn] = val;
                }
            }
        }
    }
}

// merged Q-GEMM + KV-GEMM, XCD-chunked (1176 = 8*147, bijective)
__global__ __launch_bounds__(256) void gemm_qkv_k(const ushort* __restrict__ qin,
                                                  const ushort* __restrict__ sbuf,
                                                  const ushort* __restrict__ wqb,
                                                  const ushort* __restrict__ wkvb,
                                                  const float* __restrict__ qb,
                                                  const float* __restrict__ kvb,
                                                  ushort* __restrict__ qs,
                                                  ushort* __restrict__ kb,
                                                  ushort* __restrict__ vtb) {
    __shared__ __align__(16) ushort As[128 * 32];
    __shared__ __align__(16) ushort Bs[128 * 32];
    int d = blockIdx.x;
    int w = (d & 7) * 147 + (d >> 3);
    if (w < 588) {
        int by = w / 6, bx = w % 6;
        gemm_body<0>(As, Bs, qin, wqb, qb, qs, nullptr, nullptr, by * 128, bx * 128);
    } else {
        int w2 = w - 588;
        int by = w2 / 12, bx = w2 % 12;
        gemm_body<1>(As, Bs, sbuf, wkvb, kvb, kb, vtb, nullptr, by * 128, bx * 128);
    }
}

// proj GEMM, XCD-chunked (588 = 8*73 + 4 -> bijective variant)
__global__ __launch_bounds__(256) void gemm_proj_k(const ushort* __restrict__ ob,
                                                   const ushort* __restrict__ wpjb,
                                                   const float* __restrict__ pjb,
                                                   float* __restrict__ out) {
    __shared__ __align__(16) ushort As[128 * 32];
    __shared__ __align__(16) ushort Bs[128 * 32];
    int d = blockIdx.x;
    int xcd = d & 7;
    int w = (xcd < 4 ? xcd * 74 : 296 + (xcd - 4) * 73) + (d >> 3);
    int by = w / 6, bx = w % 6;
    gemm_body<2>(As, Bs, ob, wpjb, pjb, nullptr, nullptr, out, by * 128, bx * 128);
}

// ---------------- attention (R12 config + ROLLED main loop) ----------------
// Identical dataflow to the 68.5us R12 kernel (swapped-operand, packed-V 16-col,
// K prefetch-distance-2 triple-buffer, V distance-1 double-buffer, 1344 blocks
// bh-major, 2 waves, NT=4/3, setprio). ONLY change: the 24-group loop is rolled
// (#pragma unroll 1) with explicit register rotation (kA<-kB<-kC, vA<-vB) instead
// of LCM-6 unrolling — shrinks the hot loop body ~6x to fight I-cache thrash
// (hypothesis for the 4-5x issue-vs-wall gap; loads are already prefetched
// 2700+ cycles ahead so data latency cannot explain the stall).

template <int NT>
__device__ __forceinline__ void attn_wave(const ushort* __restrict__ q,
                                          const ushort* __restrict__ kp,
                                          const ushort* __restrict__ vtp,
                                          ushort* __restrict__ obuf,
                                          int bh, int b, int h, int m0, int lane) {
    const int lr = lane & 15, hi = lane >> 4;

    bf16x8 qa0[NT], qa1[NT];
#pragma unroll
    for (int t = 0; t < NT; ++t) {
        const ushort* qp = q + ((size_t)bh * MQ + m0 + t * 16 + lr) * HD;
        qa0[t] = *(const bf16x8*)(qp + hi * 8);
        qa1[t] = *(const bf16x8*)(qp + 32 + hi * 8);
    }

    f32x4 oacc[NT][4] = {};
    float lsum[NT] = {};

    // K triple-buffer (dist 2), V double-buffer (dist 1)
    bf16x8 kA[4], kB[4], kC[4];
    bf16x4 vAa[4], vAb[4], vBa[4], vBb[4];
    {
        const ushort* ka = kp + (size_t)lr * HD + hi * 8;
        kA[0] = *(const bf16x8*)ka;
        kA[1] = *(const bf16x8*)(ka + 32);
        kA[2] = *(const bf16x8*)(ka + 16 * HD);
        kA[3] = *(const bf16x8*)(ka + 16 * HD + 32);
        const ushort* kb1 = ka + 32 * HD;
        kB[0] = *(const bf16x8*)kb1;
        kB[1] = *(const bf16x8*)(kb1 + 32);
        kB[2] = *(const bf16x8*)(kb1 + 16 * HD);
        kB[3] = *(const bf16x8*)(kb1 + 16 * HD + 32);
        const ushort* vp = vtp + (lr * 16 + hi * 4);
#pragma unroll
        for (int db = 0; db < 4; ++db) {
            vAa[db] = *(const bf16x4*)(vp + db * 256);
            vAb[db] = *(const bf16x4*)(vp + db * 256 + 1024);
        }
    }

#pragma unroll 1
    for (int g = 0; g < 24; ++g) {
        const int nk = g * 32 + 64;   // K prefetch: group g+2 -> kC
        const int nv = g * 32 + 32;   // V prefetch: group g+1 -> vB
        {
            const ushort* ka = kp + (size_t)(nk + lr) * HD + hi * 8;
            kC[0] = *(const bf16x8*)ka;
            kC[1] = *(const bf16x8*)(ka + 32);
            kC[2] = *(const bf16x8*)(ka + 16 * HD);
            kC[3] = *(const bf16x8*)(ka + 16 * HD + 32);
        }
        {
            const ushort* vp = vtp + (size_t)(nv >> 4) * 1024 + (lr * 16 + hi * 4);
#pragma unroll
            for (int db = 0; db < 4; ++db) {
                vBa[db] = *(const bf16x4*)(vp + db * 256);
                vBb[db] = *(const bf16x4*)(vp + db * 256 + 1024);
            }
        }
        __builtin_amdgcn_s_setprio(1);
#pragma unroll
        for (int t = 0; t < NT; ++t) {
            f32x4 sA = {}, sB = {};
            sA = __builtin_amdgcn_mfma_f32_16x16x32_bf16(kA[0], qa0[t], sA, 0, 0, 0);
            sA = __builtin_amdgcn_mfma_f32_16x16x32_bf16(kA[1], qa1[t], sA, 0, 0, 0);
            sB = __builtin_amdgcn_mfma_f32_16x16x32_bf16(kA[2], qa0[t], sB, 0, 0, 0);
            sB = __builtin_amdgcn_mfma_f32_16x16x32_bf16(kA[3], qa1[t], sB, 0, 0, 0);
            float eA0 = fexp2(sA[0]), eA1 = fexp2(sA[1]), eA2 = fexp2(sA[2]), eA3 = fexp2(sA[3]);
            float eB0 = fexp2(sB[0]), eB1 = fexp2(sB[1]), eB2 = fexp2(sB[2]), eB3 = fexp2(sB[3]);
            lsum[t] += ((eA0 + eA1) + (eA2 + eA3)) + ((eB0 + eB1) + (eB2 + eB3));
            union { uint4 w; bf16x8 v; } pk;
            pk.w.x = pk2(eA0, eA1);
            pk.w.y = pk2(eA2, eA3);
            pk.w.z = pk2(eB0, eB1);
            pk.w.w = pk2(eB2, eB3);
#pragma unroll
            for (int db = 0; db < 4; ++db) {
                union { struct { bf16x4 lo, hi_; } s; bf16x8 v; } vf;
                vf.s.lo = vAa[db]; vf.s.hi_ = vAb[db];
                oacc[t][db] = __builtin_amdgcn_mfma_f32_16x16x32_bf16(pk.v, vf.v, oacc[t][db], 0, 0, 0);
            }
        }
        __builtin_amdgcn_s_setprio(0);
        // rotate buffers: kA <- kB <- kC, vA <- vB
#pragma unroll
        for (int i = 0; i < 4; ++i) { kA[i] = kB[i]; kB[i] = kC[i]; }
#pragma unroll
        for (int i = 0; i < 4; ++i) { vAa[i] = vBa[i]; vAb[i] = vBb[i]; }
    }

    // tail: cols 768..783 — kA holds K group 24, vAa holds V g2=48
    {
#pragma unroll
        for (int t = 0; t < NT; ++t) {
            f32x4 sA = {};
            sA = __builtin_amdgcn_mfma_f32_16x16x32_bf16(kA[0], qa0[t], sA, 0, 0, 0);
            sA = __builtin_amdgcn_mfma_f32_16x16x32_bf16(kA[1], qa1[t], sA, 0, 0, 0);
            float eA0 = fexp2(sA[0]), eA1 = fexp2(sA[1]), eA2 = fexp2(sA[2]), eA3 = fexp2(sA[3]);
            lsum[t] += (eA0 + eA1) + (eA2 + eA3);
            union { uint4 w; bf16x8 v; } pk;
            pk.w.x = pk2(eA0, eA1);
            pk.w.y = pk2(eA2, eA3);
            pk.w.z = 0;
            pk.w.w = 0;
#pragma unroll
            for (int db = 0; db < 4; ++db) {
                union { struct { bf16x4 lo, hi_; } s; bf16x8 v; } vf;
                vf.s.lo = vAa[db]; vf.s.hi_ = vAa[db];   // hi half multiplied by 0
                oacc[t][db] = __builtin_amdgcn_mfma_f32_16x16x32_bf16(pk.v, vf.v, oacc[t][db], 0, 0, 0);
            }
        }
    }

    // epilogue: lane (hi,lr) has partial row-sum for m=lr; reduce over hi-groups,
    // broadcast to the output fragment rows (m = 4*hi+r), normalize, store.
#pragma unroll
    for (int t = 0; t < NT; ++t) {
        float sum = lsum[t];
        sum += __shfl_xor(sum, 16);
        sum += __shfl_xor(sum, 32);
        float inv = 1.0f / sum;   // valid for row m = lr
#pragma unroll
        for (int r = 0; r < 4; ++r) {
            float invr = __shfl(inv, hi * 4 + r);
            int m = m0 + t * 16 + hi * 4 + r;
            ushort* op = obuf + ((size_t)b * MQ + m) * DIM + h * HD;
#pragma unroll
            for (int db = 0; db < 4; ++db)
                op[db * 16 + lr] = f2bf(oacc[t][db][r] * invr);
        }
    }
}

__global__ __launch_bounds__(128) void attn_k(const ushort* __restrict__ q,
                                              const ushort* __restrict__ kbuf,
                                              const ushort* __restrict__ vt,
                                              ushort* __restrict__ obuf) {
    const int lane = threadIdx.x & 63, wid = threadIdx.x >> 6;
    const int bid = blockIdx.x;
    const int bh = bid % 96;           // bh-major: all mb of one bh share bid%8 -> one XCD
    const int mb = bid / 96;
    const int b = bh / NHEAD, h = bh % NHEAD;
    const ushort* kp  = kbuf + (size_t)bh * NKV * HD;
    const ushort* vtp = vt + (size_t)bh * NG2 * 1024;
    const int mbase = mb * 112;
    if (wid == 0)
        attn_wave<4>(q, kp, vtp, obuf, bh, b, h, mbase, lane);
    else
        attn_wave<3>(q, kp, vtp, obuf, bh, b, h, mbase + 64, lane);
}

// ---------------- launch ----------------

extern "C" void kernel_launch(void* const* d_in, const int* in_sizes, int n_in,
                              void* d_out, int out_size, void* d_ws, size_t ws_size,
                              hipStream_t stream) {
    const float* s_x  = (const float*)d_in[0];
    const float* t_x  = (const float*)d_in[1];
    const float* csp  = (const float*)d_in[2];
    const float* ctp  = (const float*)d_in[3];
    const float* vsp  = (const float*)d_in[4];
    const float* vtp  = (const float*)d_in[5];
    const float* Wq   = (const float*)d_in[6];
    const float* qb   = (const float*)d_in[7];
    const float* Wkv  = (const float*)d_in[8];
    const float* kvb  = (const float*)d_in[9];
    const float* Wpj  = (const float*)d_in[10];
    const float* pjb  = (const float*)d_in[11];
    float* out = (float*)d_out;

    ushort* w = (ushort*)d_ws;
    ushort* qin  = w; w += (size_t)B_ * MQ * DIM;
    ushort* sb   = w; w += (size_t)B_ * NKV * DIM;
    ushort* wqb  = w; w += (size_t)DIM * DIM;
    ushort* wkvb = w; w += (size_t)2 * DIM * DIM;
    ushort* wpjb = w; w += (size_t)DIM * DIM;
    ushort* qs   = w; w += (size_t)B_ * NHEAD * MQ * HD;
    ushort* kb   = w; w += (size_t)B_ * NHEAD * NKV * HD;
    ushort* vtb  = w; w += (size_t)B_ * NHEAD * NG2 * 1024;  // packed V (16-col groups)
    ushort* ob   = w; w += (size_t)B_ * MQ * DIM;

    prep_all_k<<<16464, 256, 0, stream>>>(t_x, vsp, vtp, s_x, csp, ctp,
                                          Wq, Wkv, Wpj,
                                          qin, sb, wqb, wkvb, wpjb, out);

    gemm_qkv_k<<<1176, 256, 0, stream>>>(qin, sb, wqb, wkvb, qb, kvb, qs, kb, vtb);

    attn_k<<<1344, 128, 0, stream>>>(qs, kb, vtb, ob);

    gemm_proj_k<<<588, 256, 0, stream>>>(ob, wpjb, pjb, out);
}

// Round 17
// 152.102 us; speedup vs baseline: 1.0513x; 1.0513x over previous
//
#include <hip/hip_runtime.h>
#include <stdint.h>

#define DIM 768
#define NHEAD 12
#define HD 64
#define B_ 8
#define SPEC 4
#define T_ 8
#define AP 196
#define VP 196
#define MQ (VP*T_)      // 1568
#define NKV (AP*SPEC)   // 784
#define NG2 50          // 16-col V groups per bh (49 used + 1 overread pad)
#define QSCALE 0.1803368801111618f   // 0.125 * log2(e): softmax done in exp2 domain

typedef short bf16x8 __attribute__((ext_vector_type(8)));
typedef short bf16x4 __attribute__((ext_vector_type(4)));
typedef float f32x4 __attribute__((ext_vector_type(4)));

__device__ __forceinline__ ushort f2bf(float f) {
    union { float f; unsigned u; } v; v.f = f;
    unsigned u = v.u;
    return (ushort)((u + 0x7fffu + ((u >> 16) & 1u)) >> 16);
}

__device__ __forceinline__ float fexp2(float x) {
    float r;
    asm("v_exp_f32 %0, %1" : "=v"(r) : "v"(x));
    return r;   // 2^x
}

// pack two f32 -> {lo = trunc-bf16(a), hi = trunc-bf16(b)} (proven bit-op path)
__device__ __forceinline__ unsigned pk2(float a, float b) {
    union { float f; unsigned u; } ua, ub; ua.f = a; ub.f = b;
    return (ub.u & 0xFFFF0000u) | (ua.u >> 16);
}

typedef const __attribute__((address_space(1))) void GV;
typedef __attribute__((address_space(3))) void LV;
__device__ __forceinline__ void gload16(const void* g, void* l) {
    __builtin_amdgcn_global_load_lds((GV*)g, (LV*)l, 16, 0, 0);
}

// ---------------- merged prep kernel (range-dispatched) ----------------

__global__ void prep_all_k(const float* __restrict__ t_x,
                           const float* __restrict__ vsp,
                           const float* __restrict__ vtp,
                           const float* __restrict__ s_x,
                           const float* __restrict__ csp,
                           const float* __restrict__ ctp,
                           const float* __restrict__ Wq,
                           const float* __restrict__ Wkv,
                           const float* __restrict__ Wpj,
                           ushort* __restrict__ qin,
                           ushort* __restrict__ sb,
                           ushort* __restrict__ wqb,
                           ushort* __restrict__ wkvb,
                           ushort* __restrict__ wpjb,
                           float* __restrict__ out) {
    int bid = blockIdx.x;
    if (bid < 9408) {
        int i = bid * 256 + threadIdx.x;
        int d4 = i % (DIM / 4);
        int rest = i / (DIM / 4);
        int m = rest % MQ;
        int b = rest / MQ;
        int vp = m >> 3, t = m & 7;
        const float4 a  = *(const float4*)(t_x + ((size_t)(1 + vp) * (B_ * T_) + b * T_ + t) * DIM + d4 * 4);
        const float4 p1 = *(const float4*)(vsp + (size_t)vp * DIM + d4 * 4);
        const float4 p2 = *(const float4*)(vtp + (size_t)t * DIM + d4 * 4);
        ushort4 r;
        r.x = f2bf(a.x + p1.x + p2.x);
        r.y = f2bf(a.y + p1.y + p2.y);
        r.z = f2bf(a.z + p1.z + p2.z);
        r.w = f2bf(a.w + p1.w + p2.w);
        *(ushort4*)(qin + ((size_t)(b * MQ + m)) * DIM + d4 * 4) = r;
    } else if (bid < 14112) {
        int i = (bid - 9408) * 256 + threadIdx.x;
        int d4 = i % (DIM / 4);
        int rest = i / (DIM / 4);
        int n = rest % NKV;
        int b = rest / NKV;
        int ap = n >> 2, spec = n & 3;
        const float4 a  = *(const float4*)(s_x + ((size_t)ap * (B_ * SPEC) + b * SPEC + spec) * DIM + d4 * 4);
        const float4 p1 = *(const float4*)(csp + (size_t)ap * DIM + d4 * 4);
        const float4 p2 = *(const float4*)(ctp + (size_t)spec * DIM + d4 * 4);
        ushort4 r;
        r.x = f2bf(a.x + p1.x + p2.x);
        r.y = f2bf(a.y + p1.y + p2.y);
        r.z = f2bf(a.z + p1.z + p2.z);
        r.w = f2bf(a.w + p1.w + p2.w);
        *(ushort4*)(sb + ((size_t)(b * NKV + n)) * DIM + d4 * 4) = r;
    } else if (bid < 16416) {
        const float* src; ushort* dst; int i;
        if (bid < 14688)      { src = Wq;  dst = wqb;  i = (bid - 14112) * 256 + threadIdx.x; }
        else if (bid < 15840) { src = Wkv; dst = wkvb; i = (bid - 14688) * 256 + threadIdx.x; }
        else                  { src = Wpj; dst = wpjb; i = (bid - 15840) * 256 + threadIdx.x; }
        float4 v = *(const float4*)(src + (size_t)i * 4);
        ushort4 r;
        r.x = f2bf(v.x); r.y = f2bf(v.y); r.z = f2bf(v.z); r.w = f2bf(v.w);
        *(ushort4*)(dst + (size_t)i * 4) = r;
    } else {
        int i = (bid - 16416) * 256 + threadIdx.x;
        *(float4*)(out + (size_t)i * 4) = *(const float4*)(t_x + (size_t)i * 4);
    }
}

// ---------------- GEMM core (128x128 tile, BK=32, 4 waves, bf16 MFMA) ----------------
// MODE 1 V half stores into the PACKED fragment layout:
// vpk[bh][g2][d][c], g2 = n/16, c = n%16  (each (mi,ni) tile = one 512B block)

template <int MODE>
__device__ __forceinline__ void gemm_body(ushort* As, ushort* Bs,
                                          const ushort* __restrict__ A,
                                          const ushort* __restrict__ Bw,
                                          const float* __restrict__ bias,
                                          ushort* __restrict__ out_a,
                                          ushort* __restrict__ out_b,
                                          float* __restrict__ out_f,
                                          int m0, int n0) {
    const int tid = threadIdx.x;
    const int lane = tid & 63, wid = tid >> 6;
    const int wm = wid >> 1, wn = wid & 1;
    const int lr = lane & 15, hi = lane >> 4;

    const int srow = wid * 32 + (lane >> 2);
    const int scolb = (lane & 3) * 16;
    const char* gA = (const char*)A + ((size_t)(m0 + srow) * DIM) * 2 + scolb;
    const char* gB = (const char*)Bw + ((size_t)(n0 + srow) * DIM) * 2 + scolb;
    const size_t radv = (size_t)16 * DIM * 2;
    char* lA = (char*)As + wid * 2048;
    char* lB = (char*)Bs + wid * 2048;

    f32x4 acc[4][4] = {};

    for (int k0 = 0; k0 < DIM; k0 += 32) {
        size_t ko = (size_t)k0 * 2;
        gload16(gA + ko,        lA);
        gload16(gA + ko + radv, lA + 1024);
        gload16(gB + ko,        lB);
        gload16(gB + ko + radv, lB + 1024);
        __syncthreads();
        bf16x8 af[4], bfr[4];
#pragma unroll
        for (int x = 0; x < 4; ++x) {
            af[x]  = *(const bf16x8*)&As[(wm * 64 + x * 16 + lr) * 32 + hi * 8];
            bfr[x] = *(const bf16x8*)&Bs[(wn * 64 + x * 16 + lr) * 32 + hi * 8];
        }
#pragma unroll
        for (int mi = 0; mi < 4; ++mi)
#pragma unroll
            for (int ni = 0; ni < 4; ++ni)
                acc[mi][ni] = __builtin_amdgcn_mfma_f32_16x16x32_bf16(af[mi], bfr[ni], acc[mi][ni], 0, 0, 0);
        __syncthreads();
    }

#pragma unroll
    for (int mi = 0; mi < 4; ++mi) {
#pragma unroll
        for (int ni = 0; ni < 4; ++ni) {
            int gn = n0 + wn * 64 + ni * 16 + lr;
            float bv = bias[gn];
            if (MODE == 1 && gn >= DIM) {
                int o2 = gn - DIM;
                int hh = o2 >> 6, d = o2 & 63;
                int gm0 = m0 + wm * 64 + mi * 16 + hi * 4;
                int b = gm0 / NKV, n = gm0 % NKV;
                int bh = b * NHEAD + hh;
                int g2 = n >> 4, c = n & 15;
                ushort4 pk;
                pk.x = f2bf(acc[mi][ni][0] + bv);
                pk.y = f2bf(acc[mi][ni][1] + bv);
                pk.z = f2bf(acc[mi][ni][2] + bv);
                pk.w = f2bf(acc[mi][ni][3] + bv);
                *(ushort4*)&out_b[(((size_t)(bh * NG2 + g2)) * 64 + d) * 16 + c] = pk;
                continue;
            }
#pragma unroll
            for (int r = 0; r < 4; ++r) {
                int gm = m0 + wm * 64 + mi * 16 + hi * 4 + r;
                float val = acc[mi][ni][r] + bv;
                if (MODE == 0) {
                    int b = gm / MQ, m = gm % MQ;
                    int hh = gn >> 6, d = gn & 63;
                    out_a[(((size_t)(b * NHEAD + hh)) * MQ + m) * HD + d] = f2bf(val * QSCALE);
                } else if (MODE == 1) {
                    int b = gm / NKV, n = gm % NKV;
                    int hh = gn >> 6, d = gn & 63;
                    out_a[(((size_t)(b * NHEAD + hh)) * NKV + n) * HD + d] = f2bf(val);
                } else {
                    int b = gm / MQ, m = gm % MQ;
                    int vp = m >> 3, tt = m & 7;
                    out_f[((size_t)(1 + vp) * (B_ * T_) + b * T_ + tt) * DIM + gn] = val;
                }
            }
        }
    }
}

// merged Q-GEMM + KV-GEMM, XCD-chunked (1176 = 8*147, bijective)
__global__ __launch_bounds__(256) void gemm_qkv_k(const ushort* __restrict__ qin,
                                                  const ushort* __restrict__ sbuf,
                                                  const ushort* __restrict__ wqb,
                                                  const ushort* __restrict__ wkvb,
                                                  const float* __restrict__ qb,
                                                  const float* __restrict__ kvb,
                                                  ushort* __restrict__ qs,
                                                  ushort* __restrict__ kb,
                                                  ushort* __restrict__ vtb) {
    __shared__ __align__(16) ushort As[128 * 32];
    __shared__ __align__(16) ushort Bs[128 * 32];
    int d = blockIdx.x;
    int w = (d & 7) * 147 + (d >> 3);
    if (w < 588) {
        int by = w / 6, bx = w % 6;
        gemm_body<0>(As, Bs, qin, wqb, qb, qs, nullptr, nullptr, by * 128, bx * 128);
    } else {
        int w2 = w - 588;
        int by = w2 / 12, bx = w2 % 12;
        gemm_body<1>(As, Bs, sbuf, wkvb, kvb, kb, vtb, nullptr, by * 128, bx * 128);
    }
}

// proj GEMM, XCD-chunked (588 = 8*73 + 4 -> bijective variant)
__global__ __launch_bounds__(256) void gemm_proj_k(const ushort* __restrict__ ob,
                                                   const ushort* __restrict__ wpjb,
                                                   const float* __restrict__ pjb,
                                                   float* __restrict__ out) {
    __shared__ __align__(16) ushort As[128 * 32];
    __shared__ __align__(16) ushort Bs[128 * 32];
    int d = blockIdx.x;
    int xcd = d & 7;
    int w = (xcd < 4 ? xcd * 74 : 296 + (xcd - 4) * 73) + (d >> 3);
    int by = w / 6, bx = w % 6;
    gemm_body<2>(As, Bs, ob, wpjb, pjb, nullptr, nullptr, out, by * 128, bx * 128);
}

// ---------------- attention (R12 config, best measured: 68.5us) ----------------
// swapped-operand, packed-V (16-col groups), K prefetch-distance-2 (triple-buffer),
// V distance-1 (double-buffer), 1344 blocks bh-major (XCD L2 pinning), 128 thr =
// 2 waves, NT=4/3, setprio. QK^T swapped: S^T = mfma(K, Q); PV via 16x16x32 with
// k<->n bijection n(8*hi+j) = 16*(j>=4) + 4*hi + (j&3). No-max softmax, exp2 domain.
// NOTE: LCM-6 unrolled rotation is LOAD-BEARING (R16: rolled loop + mov-rotation
// cost +10us). Deep prefetch (R13) and BK=64 (R14) also regress — do not revisit.

template <int NT>
__device__ __forceinline__ void attn_wave(const ushort* __restrict__ q,
                                          const ushort* __restrict__ kp,
                                          const ushort* __restrict__ vtp,
                                          ushort* __restrict__ obuf,
                                          int bh, int b, int h, int m0, int lane) {
    const int lr = lane & 15, hi = lane >> 4;

    bf16x8 qa0[NT], qa1[NT];
#pragma unroll
    for (int t = 0; t < NT; ++t) {
        const ushort* qp = q + ((size_t)bh * MQ + m0 + t * 16 + lr) * HD;
        qa0[t] = *(const bf16x8*)(qp + hi * 8);
        qa1[t] = *(const bf16x8*)(qp + 32 + hi * 8);
    }

    f32x4 oacc[NT][4] = {};
    float lsum[NT] = {};

    // K triple-buffer, V double-buffer
    bf16x8 kA[4], kB[4], kC[4];
    bf16x4 vAa[4], vAb[4], vBa[4], vBb[4];
    {
        const ushort* ka = kp + (size_t)lr * HD + hi * 8;
        kA[0] = *(const bf16x8*)ka;
        kA[1] = *(const bf16x8*)(ka + 32);
        kA[2] = *(const bf16x8*)(ka + 16 * HD);
        kA[3] = *(const bf16x8*)(ka + 16 * HD + 32);
        const ushort* kb1 = ka + 32 * HD;
        kB[0] = *(const bf16x8*)kb1;
        kB[1] = *(const bf16x8*)(kb1 + 32);
        kB[2] = *(const bf16x8*)(kb1 + 16 * HD);
        kB[3] = *(const bf16x8*)(kb1 + 16 * HD + 32);
        const ushort* vp = vtp + (lr * 16 + hi * 4);
#pragma unroll
        for (int db = 0; db < 4; ++db) {
            vAa[db] = *(const bf16x4*)(vp + db * 256);
            vAb[db] = *(const bf16x4*)(vp + db * 256 + 1024);
        }
    }

    auto gbody = [&](bf16x8* kc, bf16x8* kpre, bf16x4* vca, bf16x4* vcb,
                     bf16x4* vna, bf16x4* vnb, int g) {
        const int nk = g * 32 + 64;   // K prefetch: group g+2
        const int nv = g * 32 + 32;   // V prefetch: group g+1
        {
            const ushort* ka = kp + (size_t)(nk + lr) * HD + hi * 8;
            kpre[0] = *(const bf16x8*)ka;
            kpre[1] = *(const bf16x8*)(ka + 32);
            kpre[2] = *(const bf16x8*)(ka + 16 * HD);
            kpre[3] = *(const bf16x8*)(ka + 16 * HD + 32);
        }
        {
            const ushort* vp = vtp + (size_t)(nv >> 4) * 1024 + (lr * 16 + hi * 4);
#pragma unroll
            for (int db = 0; db < 4; ++db) {
                vna[db] = *(const bf16x4*)(vp + db * 256);
                vnb[db] = *(const bf16x4*)(vp + db * 256 + 1024);
            }
        }
        __builtin_amdgcn_s_setprio(1);
#pragma unroll
        for (int t = 0; t < NT; ++t) {
            f32x4 sA = {}, sB = {};
            sA = __builtin_amdgcn_mfma_f32_16x16x32_bf16(kc[0], qa0[t], sA, 0, 0, 0);
            sA = __builtin_amdgcn_mfma_f32_16x16x32_bf16(kc[1], qa1[t], sA, 0, 0, 0);
            sB = __builtin_amdgcn_mfma_f32_16x16x32_bf16(kc[2], qa0[t], sB, 0, 0, 0);
            sB = __builtin_amdgcn_mfma_f32_16x16x32_bf16(kc[3], qa1[t], sB, 0, 0, 0);
            float eA0 = fexp2(sA[0]), eA1 = fexp2(sA[1]), eA2 = fexp2(sA[2]), eA3 = fexp2(sA[3]);
            float eB0 = fexp2(sB[0]), eB1 = fexp2(sB[1]), eB2 = fexp2(sB[2]), eB3 = fexp2(sB[3]);
            lsum[t] += ((eA0 + eA1) + (eA2 + eA3)) + ((eB0 + eB1) + (eB2 + eB3));
            union { uint4 w; bf16x8 v; } pk;
            pk.w.x = pk2(eA0, eA1);
            pk.w.y = pk2(eA2, eA3);
            pk.w.z = pk2(eB0, eB1);
            pk.w.w = pk2(eB2, eB3);
#pragma unroll
            for (int db = 0; db < 4; ++db) {
                union { struct { bf16x4 lo, hi_; } s; bf16x8 v; } vf;
                vf.s.lo = vca[db]; vf.s.hi_ = vcb[db];
                oacc[t][db] = __builtin_amdgcn_mfma_f32_16x16x32_bf16(pk.v, vf.v, oacc[t][db], 0, 0, 0);
            }
        }
        __builtin_amdgcn_s_setprio(0);
    };

    for (int gp = 0; gp < 24; gp += 6) {
        gbody(kA, kC, vAa, vAb, vBa, vBb, gp);
        gbody(kB, kA, vBa, vBb, vAa, vAb, gp + 1);
        gbody(kC, kB, vAa, vAb, vBa, vBb, gp + 2);
        gbody(kA, kC, vBa, vBb, vAa, vAb, gp + 3);
        gbody(kB, kA, vAa, vAb, vBa, vBb, gp + 4);
        gbody(kC, kB, vBa, vBb, vAa, vAb, gp + 5);
    }

    // tail: cols 768..783 — kA holds K group 24, vAa holds V g2=48
    {
#pragma unroll
        for (int t = 0; t < NT; ++t) {
            f32x4 sA = {};
            sA = __builtin_amdgcn_mfma_f32_16x16x32_bf16(kA[0], qa0[t], sA, 0, 0, 0);
            sA = __builtin_amdgcn_mfma_f32_16x16x32_bf16(kA[1], qa1[t], sA, 0, 0, 0);
            float eA0 = fexp2(sA[0]), eA1 = fexp2(sA[1]), eA2 = fexp2(sA[2]), eA3 = fexp2(sA[3]);
            lsum[t] += (eA0 + eA1) + (eA2 + eA3);
            union { uint4 w; bf16x8 v; } pk;
            pk.w.x = pk2(eA0, eA1);
            pk.w.y = pk2(eA2, eA3);
            pk.w.z = 0;
            pk.w.w = 0;
#pragma unroll
            for (int db = 0; db < 4; ++db) {
                union { struct { bf16x4 lo, hi_; } s; bf16x8 v; } vf;
                vf.s.lo = vAa[db]; vf.s.hi_ = vAa[db];   // hi half multiplied by 0
                oacc[t][db] = __builtin_amdgcn_mfma_f32_16x16x32_bf16(pk.v, vf.v, oacc[t][db], 0, 0, 0);
            }
        }
    }

#pragma unroll
    for (int t = 0; t < NT; ++t) {
        float sum = lsum[t];
        sum += __shfl_xor(sum, 16);
        sum += __shfl_xor(sum, 32);
        float inv = 1.0f / sum;   // valid for row m = lr
#pragma unroll
        for (int r = 0; r < 4; ++r) {
            float invr = __shfl(inv, hi * 4 + r);
            int m = m0 + t * 16 + hi * 4 + r;
            ushort* op = obuf + ((size_t)b * MQ + m) * DIM + h * HD;
#pragma unroll
            for (int db = 0; db < 4; ++db)
                op[db * 16 + lr] = f2bf(oacc[t][db][r] * invr);
        }
    }
}

__global__ __launch_bounds__(128) void attn_k(const ushort* __restrict__ q,
                                              const ushort* __restrict__ kbuf,
                                              const ushort* __restrict__ vt,
                                              ushort* __restrict__ obuf) {
    const int lane = threadIdx.x & 63, wid = threadIdx.x >> 6;
    const int bid = blockIdx.x;
    const int bh = bid % 96;           // bh-major: all mb of one bh share bid%8 -> one XCD
    const int mb = bid / 96;
    const int b = bh / NHEAD, h = bh % NHEAD;
    const ushort* kp  = kbuf + (size_t)bh * NKV * HD;
    const ushort* vtp = vt + (size_t)bh * NG2 * 1024;
    const int mbase = mb * 112;
    if (wid == 0)
        attn_wave<4>(q, kp, vtp, obuf, bh, b, h, mbase, lane);
    else
        attn_wave<3>(q, kp, vtp, obuf, bh, b, h, mbase + 64, lane);
}

// ---------------- launch ----------------

extern "C" void kernel_launch(void* const* d_in, const int* in_sizes, int n_in,
                              void* d_out, int out_size, void* d_ws, size_t ws_size,
                              hipStream_t stream) {
    const float* s_x  = (const float*)d_in[0];
    const float* t_x  = (const float*)d_in[1];
    const float* csp  = (const float*)d_in[2];
    const float* ctp  = (const float*)d_in[3];
    const float* vsp  = (const float*)d_in[4];
    const float* vtp  = (const float*)d_in[5];
    const float* Wq   = (const float*)d_in[6];
    const float* qb   = (const float*)d_in[7];
    const float* Wkv  = (const float*)d_in[8];
    const float* kvb  = (const float*)d_in[9];
    const float* Wpj  = (const float*)d_in[10];
    const float* pjb  = (const float*)d_in[11];
    float* out = (float*)d_out;

    ushort* w = (ushort*)d_ws;
    ushort* qin  = w; w += (size_t)B_ * MQ * DIM;
    ushort* sb   = w; w += (size_t)B_ * NKV * DIM;
    ushort* wqb  = w; w += (size_t)DIM * DIM;
    ushort* wkvb = w; w += (size_t)2 * DIM * DIM;
    ushort* wpjb = w; w += (size_t)DIM * DIM;
    ushort* qs   = w; w += (size_t)B_ * NHEAD * MQ * HD;
    ushort* kb   = w; w += (size_t)B_ * NHEAD * NKV * HD;
    ushort* vtb  = w; w += (size_t)B_ * NHEAD * NG2 * 1024;  // packed V (16-col groups)
    ushort* ob   = w; w += (size_t)B_ * MQ * DIM;

    prep_all_k<<<16464, 256, 0, stream>>>(t_x, vsp, vtp, s_x, csp, ctp,
                                          Wq, Wkv, Wpj,
                                          qin, sb, wqb, wkvb, wpjb, out);

    gemm_qkv_k<<<1176, 256, 0, stream>>>(qin, sb, wqb, wkvb, qb, kvb, qs, kb, vtb);

    attn_k<<<1344, 128, 0, stream>>>(qs, kb, vtb, ob);

    gemm_proj_k<<<588, 256, 0, stream>>>(ob, wpjb, pjb, out);
}

// Round 19
// 151.664 us; speedup vs baseline: 1.0543x; 1.0029x over previous
//
#include <hip/hip_runtime.h>
#include <stdint.h>

#define DIM 768
#define NHEAD 12
#define HD 64
#define B_ 8
#define SPEC 4
#define T_ 8
#define AP 196
#define VP 196
#define MQ (VP*T_)      // 1568
#define NKV (AP*SPEC)   // 784
#define NG2 50          // 16-col V groups per bh (49 used + 1 overread pad)
#define QSCALE 0.1803368801111618f   // 0.125 * log2(e): softmax done in exp2 domain

typedef short bf16x8 __attribute__((ext_vector_type(8)));
typedef short bf16x4 __attribute__((ext_vector_type(4)));
typedef float f32x4 __attribute__((ext_vector_type(4)));

__device__ __forceinline__ ushort f2bf(float f) {
    union { float f; unsigned u; } v; v.f = f;
    unsigned u = v.u;
    return (ushort)((u + 0x7fffu + ((u >> 16) & 1u)) >> 16);
}

__device__ __forceinline__ float fexp2(float x) {
    float r;
    asm("v_exp_f32 %0, %1" : "=v"(r) : "v"(x));
    return r;   // 2^x
}

// pack two f32 -> {lo = trunc-bf16(a), hi = trunc-bf16(b)} (proven bit-op path)
__device__ __forceinline__ unsigned pk2(float a, float b) {
    union { float f; unsigned u; } ua, ub; ua.f = a; ub.f = b;
    return (ub.u & 0xFFFF0000u) | (ua.u >> 16);
}

typedef const __attribute__((address_space(1))) void GV;
typedef __attribute__((address_space(3))) void LV;
__device__ __forceinline__ void gload16(const void* g, void* l) {
    __builtin_amdgcn_global_load_lds((GV*)g, (LV*)l, 16, 0, 0);
}

// ---------------- merged prep kernel (range-dispatched) ----------------

__global__ void prep_all_k(const float* __restrict__ t_x,
                           const float* __restrict__ vsp,
                           const float* __restrict__ vtp,
                           const float* __restrict__ s_x,
                           const float* __restrict__ csp,
                           const float* __restrict__ ctp,
                           const float* __restrict__ Wq,
                           const float* __restrict__ Wkv,
                           const float* __restrict__ Wpj,
                           ushort* __restrict__ qin,
                           ushort* __restrict__ sb,
                           ushort* __restrict__ wqb,
                           ushort* __restrict__ wkvb,
                           ushort* __restrict__ wpjb,
                           float* __restrict__ out) {
    int bid = blockIdx.x;
    if (bid < 9408) {
        int i = bid * 256 + threadIdx.x;
        int d4 = i % (DIM / 4);
        int rest = i / (DIM / 4);
        int m = rest % MQ;
        int b = rest / MQ;
        int vp = m >> 3, t = m & 7;
        const float4 a  = *(const float4*)(t_x + ((size_t)(1 + vp) * (B_ * T_) + b * T_ + t) * DIM + d4 * 4);
        const float4 p1 = *(const float4*)(vsp + (size_t)vp * DIM + d4 * 4);
        const float4 p2 = *(const float4*)(vtp + (size_t)t * DIM + d4 * 4);
        ushort4 r;
        r.x = f2bf(a.x + p1.x + p2.x);
        r.y = f2bf(a.y + p1.y + p2.y);
        r.z = f2bf(a.z + p1.z + p2.z);
        r.w = f2bf(a.w + p1.w + p2.w);
        *(ushort4*)(qin + ((size_t)(b * MQ + m)) * DIM + d4 * 4) = r;
    } else if (bid < 14112) {
        int i = (bid - 9408) * 256 + threadIdx.x;
        int d4 = i % (DIM / 4);
        int rest = i / (DIM / 4);
        int n = rest % NKV;
        int b = rest / NKV;
        int ap = n >> 2, spec = n & 3;
        const float4 a  = *(const float4*)(s_x + ((size_t)ap * (B_ * SPEC) + b * SPEC + spec) * DIM + d4 * 4);
        const float4 p1 = *(const float4*)(csp + (size_t)ap * DIM + d4 * 4);
        const float4 p2 = *(const float4*)(ctp + (size_t)spec * DIM + d4 * 4);
        ushort4 r;
        r.x = f2bf(a.x + p1.x + p2.x);
        r.y = f2bf(a.y + p1.y + p2.y);
        r.z = f2bf(a.z + p1.z + p2.z);
        r.w = f2bf(a.w + p1.w + p2.w);
        *(ushort4*)(sb + ((size_t)(b * NKV + n)) * DIM + d4 * 4) = r;
    } else if (bid < 16416) {
        const float* src; ushort* dst; int i;
        if (bid < 14688)      { src = Wq;  dst = wqb;  i = (bid - 14112) * 256 + threadIdx.x; }
        else if (bid < 15840) { src = Wkv; dst = wkvb; i = (bid - 14688) * 256 + threadIdx.x; }
        else                  { src = Wpj; dst = wpjb; i = (bid - 15840) * 256 + threadIdx.x; }
        float4 v = *(const float4*)(src + (size_t)i * 4);
        ushort4 r;
        r.x = f2bf(v.x); r.y = f2bf(v.y); r.z = f2bf(v.z); r.w = f2bf(v.w);
        *(ushort4*)(dst + (size_t)i * 4) = r;
    } else {
        int i = (bid - 16416) * 256 + threadIdx.x;
        *(float4*)(out + (size_t)i * 4) = *(const float4*)(t_x + (size_t)i * 4);
    }
}

// ---------------- GEMM core (128x128 tile, BK=32, 4 waves, bf16 MFMA) ----------------
// MODE 1 V half stores into the PACKED fragment layout:
// vpk[bh][g2][d][c], g2 = n/16, c = n%16  (each (mi,ni) tile = one 512B block)

template <int MODE>
__device__ __forceinline__ void gemm_body(ushort* As, ushort* Bs,
                                          const ushort* __restrict__ A,
                                          const ushort* __restrict__ Bw,
                                          const float* __restrict__ bias,
                                          ushort* __restrict__ out_a,
                                          ushort* __restrict__ out_b,
                                          float* __restrict__ out_f,
                                          int m0, int n0) {
    const int tid = threadIdx.x;
    const int lane = tid & 63, wid = tid >> 6;
    const int wm = wid >> 1, wn = wid & 1;
    const int lr = lane & 15, hi = lane >> 4;

    const int srow = wid * 32 + (lane >> 2);
    const int scolb = (lane & 3) * 16;
    const char* gA = (const char*)A + ((size_t)(m0 + srow) * DIM) * 2 + scolb;
    const char* gB = (const char*)Bw + ((size_t)(n0 + srow) * DIM) * 2 + scolb;
    const size_t radv = (size_t)16 * DIM * 2;
    char* lA = (char*)As + wid * 2048;
    char* lB = (char*)Bs + wid * 2048;

    f32x4 acc[4][4] = {};

    for (int k0 = 0; k0 < DIM; k0 += 32) {
        size_t ko = (size_t)k0 * 2;
        gload16(gA + ko,        lA);
        gload16(gA + ko + radv, lA + 1024);
        gload16(gB + ko,        lB);
        gload16(gB + ko + radv, lB + 1024);
        __syncthreads();
        bf16x8 af[4], bfr[4];
#pragma unroll
        for (int x = 0; x < 4; ++x) {
            af[x]  = *(const bf16x8*)&As[(wm * 64 + x * 16 + lr) * 32 + hi * 8];
            bfr[x] = *(const bf16x8*)&Bs[(wn * 64 + x * 16 + lr) * 32 + hi * 8];
        }
#pragma unroll
        for (int mi = 0; mi < 4; ++mi)
#pragma unroll
            for (int ni = 0; ni < 4; ++ni)
                acc[mi][ni] = __builtin_amdgcn_mfma_f32_16x16x32_bf16(af[mi], bfr[ni], acc[mi][ni], 0, 0, 0);
        __syncthreads();
    }

#pragma unroll
    for (int mi = 0; mi < 4; ++mi) {
#pragma unroll
        for (int ni = 0; ni < 4; ++ni) {
            int gn = n0 + wn * 64 + ni * 16 + lr;
            float bv = bias[gn];
            if (MODE == 1 && gn >= DIM) {
                int o2 = gn - DIM;
                int hh = o2 >> 6, d = o2 & 63;
                int gm0 = m0 + wm * 64 + mi * 16 + hi * 4;
                int b = gm0 / NKV, n = gm0 % NKV;
                int bh = b * NHEAD + hh;
                int g2 = n >> 4, c = n & 15;
                ushort4 pk;
                pk.x = f2bf(acc[mi][ni][0] + bv);
                pk.y = f2bf(acc[mi][ni][1] + bv);
                pk.z = f2bf(acc[mi][ni][2] + bv);
                pk.w = f2bf(acc[mi][ni][3] + bv);
                *(ushort4*)&out_b[(((size_t)(bh * NG2 + g2)) * 64 + d) * 16 + c] = pk;
                continue;
            }
#pragma unroll
            for (int r = 0; r < 4; ++r) {
                int gm = m0 + wm * 64 + mi * 16 + hi * 4 + r;
                float val = acc[mi][ni][r] + bv;
                if (MODE == 0) {
                    int b = gm / MQ, m = gm % MQ;
                    int hh = gn >> 6, d = gn & 63;
                    out_a[(((size_t)(b * NHEAD + hh)) * MQ + m) * HD + d] = f2bf(val * QSCALE);
                } else if (MODE == 1) {
                    int b = gm / NKV, n = gm % NKV;
                    int hh = gn >> 6, d = gn & 63;
                    out_a[(((size_t)(b * NHEAD + hh)) * NKV + n) * HD + d] = f2bf(val);
                } else {
                    int b = gm / MQ, m = gm % MQ;
                    int vp = m >> 3, tt = m & 7;
                    out_f[((size_t)(1 + vp) * (B_ * T_) + b * T_ + tt) * DIM + gn] = val;
                }
            }
        }
    }
}

// merged Q-GEMM + KV-GEMM, XCD-chunked (1176 = 8*147, bijective)
__global__ __launch_bounds__(256) void gemm_qkv_k(const ushort* __restrict__ qin,
                                                  const ushort* __restrict__ sbuf,
                                                  const ushort* __restrict__ wqb,
                                                  const ushort* __restrict__ wkvb,
                                                  const float* __restrict__ qb,
                                                  const float* __restrict__ kvb,
                                                  ushort* __restrict__ qs,
                                                  ushort* __restrict__ kb,
                                                  ushort* __restrict__ vtb) {
    __shared__ __align__(16) ushort As[128 * 32];
    __shared__ __align__(16) ushort Bs[128 * 32];
    int d = blockIdx.x;
    int w = (d & 7) * 147 + (d >> 3);
    if (w < 588) {
        int by = w / 6, bx = w % 6;
        gemm_body<0>(As, Bs, qin, wqb, qb, qs, nullptr, nullptr, by * 128, bx * 128);
    } else {
        int w2 = w - 588;
        int by = w2 / 12, bx = w2 % 12;
        gemm_body<1>(As, Bs, sbuf, wkvb, kvb, kb, vtb, nullptr, by * 128, bx * 128);
    }
}

// proj GEMM, XCD-chunked (588 = 8*73 + 4 -> bijective variant)
__global__ __launch_bounds__(256) void gemm_proj_k(const ushort* __restrict__ ob,
                                                   const ushort* __restrict__ wpjb,
                                                   const float* __restrict__ pjb,
                                                   float* __restrict__ out) {
    __shared__ __align__(16) ushort As[128 * 32];
    __shared__ __align__(16) ushort Bs[128 * 32];
    int d = blockIdx.x;
    int xcd = d & 7;
    int w = (xcd < 4 ? xcd * 74 : 296 + (xcd - 4) * 73) + (d >> 3);
    int by = w / 6, bx = w % 6;
    gemm_body<2>(As, Bs, ob, wpjb, pjb, nullptr, nullptr, out, by * 128, bx * 128);
}

// ---------------- attention (R12 config, best measured: 68.5us x3) ----------------
// swapped-operand, packed-V (16-col groups), K prefetch-distance-2 (triple-buffer),
// V distance-1 (double-buffer), 1344 blocks bh-major (XCD L2 pinning), 128 thr =
// 2 waves, NT=4/3, setprio. QK^T swapped: S^T = mfma(K, Q); PV via 16x16x32 with
// k<->n bijection n(8*hi+j) = 16*(j>=4) + 4*hi + (j&3). No-max softmax, exp2 domain.
// FROZEN: every structural lever A/B-tested and worse — NT=2 (+28%), KV-split (+18%),
// dist-3 (+8%), rolled loop (+15%), BK=64 GEMM (+4%), launch_bounds(128,3) (BROKEN).

template <int NT>
__device__ __forceinline__ void attn_wave(const ushort* __restrict__ q,
                                          const ushort* __restrict__ kp,
                                          const ushort* __restrict__ vtp,
                                          ushort* __restrict__ obuf,
                                          int bh, int b, int h, int m0, int lane) {
    const int lr = lane & 15, hi = lane >> 4;

    bf16x8 qa0[NT], qa1[NT];
#pragma unroll
    for (int t = 0; t < NT; ++t) {
        const ushort* qp = q + ((size_t)bh * MQ + m0 + t * 16 + lr) * HD;
        qa0[t] = *(const bf16x8*)(qp + hi * 8);
        qa1[t] = *(const bf16x8*)(qp + 32 + hi * 8);
    }

    f32x4 oacc[NT][4] = {};
    float lsum[NT] = {};

    // K triple-buffer, V double-buffer
    bf16x8 kA[4], kB[4], kC[4];
    bf16x4 vAa[4], vAb[4], vBa[4], vBb[4];
    {
        const ushort* ka = kp + (size_t)lr * HD + hi * 8;
        kA[0] = *(const bf16x8*)ka;
        kA[1] = *(const bf16x8*)(ka + 32);
        kA[2] = *(const bf16x8*)(ka + 16 * HD);
        kA[3] = *(const bf16x8*)(ka + 16 * HD + 32);
        const ushort* kb1 = ka + 32 * HD;
        kB[0] = *(const bf16x8*)kb1;
        kB[1] = *(const bf16x8*)(kb1 + 32);
        kB[2] = *(const bf16x8*)(kb1 + 16 * HD);
        kB[3] = *(const bf16x8*)(kb1 + 16 * HD + 32);
        const ushort* vp = vtp + (lr * 16 + hi * 4);
#pragma unroll
        for (int db = 0; db < 4; ++db) {
            vAa[db] = *(const bf16x4*)(vp + db * 256);
            vAb[db] = *(const bf16x4*)(vp + db * 256 + 1024);
        }
    }

    auto gbody = [&](bf16x8* kc, bf16x8* kpre, bf16x4* vca, bf16x4* vcb,
                     bf16x4* vna, bf16x4* vnb, int g) {
        const int nk = g * 32 + 64;   // K prefetch: group g+2
        const int nv = g * 32 + 32;   // V prefetch: group g+1
        {
            const ushort* ka = kp + (size_t)(nk + lr) * HD + hi * 8;
            kpre[0] = *(const bf16x8*)ka;
            kpre[1] = *(const bf16x8*)(ka + 32);
            kpre[2] = *(const bf16x8*)(ka + 16 * HD);
            kpre[3] = *(const bf16x8*)(ka + 16 * HD + 32);
        }
        {
            const ushort* vp = vtp + (size_t)(nv >> 4) * 1024 + (lr * 16 + hi * 4);
#pragma unroll
            for (int db = 0; db < 4; ++db) {
                vna[db] = *(const bf16x4*)(vp + db * 256);
                vnb[db] = *(const bf16x4*)(vp + db * 256 + 1024);
            }
        }
        __builtin_amdgcn_s_setprio(1);
#pragma unroll
        for (int t = 0; t < NT; ++t) {
            f32x4 sA = {}, sB = {};
            sA = __builtin_amdgcn_mfma_f32_16x16x32_bf16(kc[0], qa0[t], sA, 0, 0, 0);
            sA = __builtin_amdgcn_mfma_f32_16x16x32_bf16(kc[1], qa1[t], sA, 0, 0, 0);
            sB = __builtin_amdgcn_mfma_f32_16x16x32_bf16(kc[2], qa0[t], sB, 0, 0, 0);
            sB = __builtin_amdgcn_mfma_f32_16x16x32_bf16(kc[3], qa1[t], sB, 0, 0, 0);
            float eA0 = fexp2(sA[0]), eA1 = fexp2(sA[1]), eA2 = fexp2(sA[2]), eA3 = fexp2(sA[3]);
            float eB0 = fexp2(sB[0]), eB1 = fexp2(sB[1]), eB2 = fexp2(sB[2]), eB3 = fexp2(sB[3]);
            lsum[t] += ((eA0 + eA1) + (eA2 + eA3)) + ((eB0 + eB1) + (eB2 + eB3));
            union { uint4 w; bf16x8 v; } pk;
            pk.w.x = pk2(eA0, eA1);
            pk.w.y = pk2(eA2, eA3);
            pk.w.z = pk2(eB0, eB1);
            pk.w.w = pk2(eB2, eB3);
#pragma unroll
            for (int db = 0; db < 4; ++db) {
                union { struct { bf16x4 lo, hi_; } s; bf16x8 v; } vf;
                vf.s.lo = vca[db]; vf.s.hi_ = vcb[db];
                oacc[t][db] = __builtin_amdgcn_mfma_f32_16x16x32_bf16(pk.v, vf.v, oacc[t][db], 0, 0, 0);
            }
        }
        __builtin_amdgcn_s_setprio(0);
    };

    for (int gp = 0; gp < 24; gp += 6) {
        gbody(kA, kC, vAa, vAb, vBa, vBb, gp);
        gbody(kB, kA, vBa, vBb, vAa, vAb, gp + 1);
        gbody(kC, kB, vAa, vAb, vBa, vBb, gp + 2);
        gbody(kA, kC, vBa, vBb, vAa, vAb, gp + 3);
        gbody(kB, kA, vAa, vAb, vBa, vBb, gp + 4);
        gbody(kC, kB, vBa, vBb, vAa, vAb, gp + 5);
    }

    // tail: cols 768..783 — kA holds K group 24, vAa holds V g2=48
    {
#pragma unroll
        for (int t = 0; t < NT; ++t) {
            f32x4 sA = {};
            sA = __builtin_amdgcn_mfma_f32_16x16x32_bf16(kA[0], qa0[t], sA, 0, 0, 0);
            sA = __builtin_amdgcn_mfma_f32_16x16x32_bf16(kA[1], qa1[t], sA, 0, 0, 0);
            float eA0 = fexp2(sA[0]), eA1 = fexp2(sA[1]), eA2 = fexp2(sA[2]), eA3 = fexp2(sA[3]);
            lsum[t] += (eA0 + eA1) + (eA2 + eA3);
            union { uint4 w; bf16x8 v; } pk;
            pk.w.x = pk2(eA0, eA1);
            pk.w.y = pk2(eA2, eA3);
            pk.w.z = 0;
            pk.w.w = 0;
#pragma unroll
            for (int db = 0; db < 4; ++db) {
                union { struct { bf16x4 lo, hi_; } s; bf16x8 v; } vf;
                vf.s.lo = vAa[db]; vf.s.hi_ = vAa[db];   // hi half multiplied by 0
                oacc[t][db] = __builtin_amdgcn_mfma_f32_16x16x32_bf16(pk.v, vf.v, oacc[t][db], 0, 0, 0);
            }
        }
    }

#pragma unroll
    for (int t = 0; t < NT; ++t) {
        float sum = lsum[t];
        sum += __shfl_xor(sum, 16);
        sum += __shfl_xor(sum, 32);
        float inv = 1.0f / sum;   // valid for row m = lr
#pragma unroll
        for (int r = 0; r < 4; ++r) {
            float invr = __shfl(inv, hi * 4 + r);
            int m = m0 + t * 16 + hi * 4 + r;
            ushort* op = obuf + ((size_t)b * MQ + m) * DIM + h * HD;
#pragma unroll
            for (int db = 0; db < 4; ++db)
                op[db * 16 + lr] = f2bf(oacc[t][db][r] * invr);
        }
    }
}

__global__ __launch_bounds__(128) void attn_k(const ushort* __restrict__ q,
                                              const ushort* __restrict__ kbuf,
                                              const ushort* __restrict__ vt,
                                              ushort* __restrict__ obuf) {
    const int lane = threadIdx.x & 63, wid = threadIdx.x >> 6;
    const int bid = blockIdx.x;
    const int bh = bid % 96;           // bh-major: all mb of one bh share bid%8 -> one XCD
    const int mb = bid / 96;
    const int b = bh / NHEAD, h = bh % NHEAD;
    const ushort* kp  = kbuf + (size_t)bh * NKV * HD;
    const ushort* vtp = vt + (size_t)bh * NG2 * 1024;
    const int mbase = mb * 112;
    if (wid == 0)
        attn_wave<4>(q, kp, vtp, obuf, bh, b, h, mbase, lane);
    else
        attn_wave<3>(q, kp, vtp, obuf, bh, b, h, mbase + 64, lane);
}

// ---------------- launch ----------------

extern "C" void kernel_launch(void* const* d_in, const int* in_sizes, int n_in,
                              void* d_out, int out_size, void* d_ws, size_t ws_size,
                              hipStream_t stream) {
    const float* s_x  = (const float*)d_in[0];
    const float* t_x  = (const float*)d_in[1];
    const float* csp  = (const float*)d_in[2];
    const float* ctp  = (const float*)d_in[3];
    const float* vsp  = (const float*)d_in[4];
    const float* vtp  = (const float*)d_in[5];
    const float* Wq   = (const float*)d_in[6];
    const float* qb   = (const float*)d_in[7];
    const float* Wkv  = (const float*)d_in[8];
    const float* kvb  = (const float*)d_in[9];
    const float* Wpj  = (const float*)d_in[10];
    const float* pjb  = (const float*)d_in[11];
    float* out = (float*)d_out;

    ushort* w = (ushort*)d_ws;
    ushort* qin  = w; w += (size_t)B_ * MQ * DIM;
    ushort* sb   = w; w += (size_t)B_ * NKV * DIM;
    ushort* wqb  = w; w += (size_t)DIM * DIM;
    ushort* wkvb = w; w += (size_t)2 * DIM * DIM;
    ushort* wpjb = w; w += (size_t)DIM * DIM;
    ushort* qs   = w; w += (size_t)B_ * NHEAD * MQ * HD;
    ushort* kb   = w; w += (size_t)B_ * NHEAD * NKV * HD;
    ushort* vtb  = w; w += (size_t)B_ * NHEAD * NG2 * 1024;  // packed V (16-col groups)
    ushort* ob   = w; w += (size_t)B_ * MQ * DIM;

    prep_all_k<<<16464, 256, 0, stream>>>(t_x, vsp, vtp, s_x, csp, ctp,
                                          Wq, Wkv, Wpj,
                                          qin, sb, wqb, wkvb, wpjb, out);

    gemm_qkv_k<<<1176, 256, 0, stream>>>(qin, sb, wqb, wkvb, qb, kvb, qs, kb, vtb);

    attn_k<<<1344, 128, 0, stream>>>(qs, kb, vtb, ob);

    gemm_proj_k<<<588, 256, 0, stream>>>(ob, wpjb, pjb, out);
}